// Round 5
// baseline (166.931 us; speedup 1.0000x reference)
//
#include <hip/hip_runtime.h>

typedef __bf16 bf16x8 __attribute__((ext_vector_type(8)));
typedef float f32x4 __attribute__((ext_vector_type(4)));
typedef float f32x16 __attribute__((ext_vector_type(16)));
typedef unsigned short u16x8 __attribute__((ext_vector_type(8)));

constexpr int S_LEN = 2048;
constexpr int QKV1  = 2 * 16 * 2048 * 64;   // elements per Q/K/V tensor = 4194304

__device__ inline unsigned short f2bf(float f) {
    __bf16 h = (__bf16)f;
    return __builtin_bit_cast(unsigned short, h);
}

// global -> LDS async copy, 16B per lane; lds base must be wave-uniform,
// HW writes lane l at base + l*16 (m97/m104).
__device__ inline void gll16(const void* g, void* l) {
    __builtin_amdgcn_global_load_lds(
        (const __attribute__((address_space(1))) unsigned int*)g,
        (__attribute__((address_space(3))) unsigned int*)l,
        16, 0, 0);
}

// ---------------------------------------------------------------------------
// fp32 -> bf16 convert (for X), vectorized float4 -> ushort4.
// ---------------------------------------------------------------------------
__global__ __launch_bounds__(256) void cvt_f32_bf16(
    const float* __restrict__ src, unsigned short* __restrict__ dst, int n4)
{
    int i = blockIdx.x * 256 + threadIdx.x;
    if (i >= n4) return;
    float4 v = ((const float4*)src)[i];
    ushort4 u;
    u.x = f2bf(v.x); u.y = f2bf(v.y); u.z = f2bf(v.z); u.w = f2bf(v.w);
    ((ushort4*)dst)[i] = u;
}

// ---------------------------------------------------------------------------
// Transpose + convert: src [R][C] fp32 -> dst [C][R] bf16
// ---------------------------------------------------------------------------
__global__ __launch_bounds__(256) void transpose_cvt(
    const float* __restrict__ src, unsigned short* __restrict__ dst, int R, int C)
{
    __shared__ float t[32][33];
    const int c0 = blockIdx.x * 32, r0 = blockIdx.y * 32;
    const int tx = threadIdx.x, ty = threadIdx.y;
    #pragma unroll
    for (int i = 0; i < 4; ++i)
        t[ty * 4 + i][tx] = src[(size_t)(r0 + ty * 4 + i) * C + c0 + tx];
    __syncthreads();
    #pragma unroll
    for (int i = 0; i < 4; ++i)
        dst[(size_t)(c0 + ty * 4 + i) * R + r0 + tx] = f2bf(t[tx][ty * 4 + i]);
}

// ---------------------------------------------------------------------------
// m97-structure bf16 GEMM (unchanged from R4 — known-good).
// ---------------------------------------------------------------------------
template<int EPI>
__global__ __launch_bounds__(256) void gemm128(
    const unsigned short* __restrict__ A,   // [M][K] bf16
    const unsigned short* __restrict__ Bt,  // [N][K] bf16
    const float* __restrict__ bias,         // [N]
    void* __restrict__ outp, int M, int N, int K)
{
    __shared__ unsigned short As[128 * 64];
    __shared__ unsigned short Bs[128 * 64];
    const int tid = threadIdx.x, lane = tid & 63, wid = tid >> 6;
    const int q = lane & 15, g = lane >> 4;
    const int wr = wid >> 1, wc = wid & 1;

    const int nbx = N >> 7;
    const int cpx = gridDim.x >> 3;
    const int bid = blockIdx.x;
    const int swz = (bid & 7) * cpx + (bid >> 3);    // bijective, nwg%8==0
    const int m0 = (swz / nbx) * 128, n0 = (swz % nbx) * 128;

    const int lrow = lane >> 3, lcol = (lane & 7) * 8;  // within-chunk row/col

    f32x4 acc[4][4];
    #pragma unroll
    for (int i = 0; i < 4; ++i)
        #pragma unroll
        for (int j = 0; j < 4; ++j) acc[i][j] = (f32x4){0.f, 0.f, 0.f, 0.f};

    for (int k0 = 0; k0 < K; k0 += 64) {
        #pragma unroll
        for (int i = 0; i < 4; ++i) {       // 4 chunks/operand/wave, 1KB each
            int c = wid * 4 + i;
            int row = c * 8 + lrow;
            gll16(&A [(size_t)(m0 + row) * K + k0 + lcol], &As[c * 512]);
            gll16(&Bt[(size_t)(n0 + row) * K + k0 + lcol], &Bs[c * 512]);
        }
        __syncthreads();                    // compiler drains vmcnt before barrier
        #pragma unroll
        for (int h = 0; h < 2; ++h) {
            bf16x8 a[4], b[4];
            #pragma unroll
            for (int mi = 0; mi < 4; ++mi)
                a[mi] = *(const bf16x8*)&As[(wr * 64 + mi * 16 + q) * 64 + h * 32 + g * 8];
            #pragma unroll
            for (int ni = 0; ni < 4; ++ni)
                b[ni] = *(const bf16x8*)&Bs[(wc * 64 + ni * 16 + q) * 64 + h * 32 + g * 8];
            #pragma unroll
            for (int mi = 0; mi < 4; ++mi)
                #pragma unroll
                for (int ni = 0; ni < 4; ++ni)
                    acc[mi][ni] = __builtin_amdgcn_mfma_f32_16x16x32_bf16(a[mi], b[ni], acc[mi][ni], 0, 0, 0);
        }
        __syncthreads();
    }

    #pragma unroll
    for (int mi = 0; mi < 4; ++mi)
        #pragma unroll
        for (int ni = 0; ni < 4; ++ni)
            #pragma unroll
            for (int r = 0; r < 4; ++r) {
                int m = m0 + wr * 64 + mi * 16 + g * 4 + r;
                int n = n0 + wc * 64 + ni * 16 + q;
                float v = acc[mi][ni][r] + bias[n];
                if (EPI == 0) {
                    int t = n >> 10, rem = n & 1023;
                    if (t == 0) v *= 0.125f;          // q * rsqrt(64)
                    int h2 = rem >> 6, kk = rem & 63;
                    int bb = m >> 11, s = m & 2047;
                    ((unsigned short*)outp)[(size_t)t * QKV1 +
                        ((size_t)(bb * 16 + h2) * 2048 + s) * 64 + kk] = f2bf(v);
                } else {
                    ((float*)outp)[(size_t)m * N + n] = v;
                }
            }
}

// ---------------------------------------------------------------------------
// Kernel 2: causal flash attention, swapped-QK 32x32 structure.
// NOW: 2-wave blocks (128 thr), one 64-row q-tile per block, grid 32bh x 32t,
// LPT order (longest t first) -> 1024 blocks = 4 blocks/CU = 2 waves/SIMD.
// ---------------------------------------------------------------------------
__global__ __launch_bounds__(128) void attn_fwd(
    const unsigned short* __restrict__ qkv, unsigned short* __restrict__ aout)
{
    __shared__ unsigned short Ks[2][64][72];
    __shared__ unsigned short Vs[2][64][72];   // transposed: [d][kv]
    __shared__ float cLds[2][32];
    const int tid = threadIdx.x, lane = tid & 63, wid = tid >> 6;
    const int hi = lane >> 5, lq = lane & 31;
    const int bh = blockIdx.x;
    const int t  = 31 - (int)blockIdx.y;        // LPT: longest blocks first
    const int NJ = t + 1;
    const unsigned short* Qg = qkv + (size_t)bh * S_LEN * 64;
    const unsigned short* Kg = qkv + (size_t)QKV1 + (size_t)bh * S_LEN * 64;
    const unsigned short* Vg = qkv + 2 * (size_t)QKV1 + (size_t)bh * S_LEN * 64;

    // staging: 128 threads, contiguous 16B/lane chunks (2KB per instruction)
    const int srr = tid >> 3, scc = (tid & 7) * 8;
    u16x8 kr[4], vr[4];
    auto stage_load = [&](int j0) {
        #pragma unroll
        for (int p = 0; p < 4; ++p) {
            kr[p] = *(const u16x8*)&Kg[(size_t)(j0 + srr + p * 16) * 64 + scc];
            vr[p] = *(const u16x8*)&Vg[(size_t)(j0 + srr + p * 16) * 64 + scc];
        }
    };
    auto stage_write = [&](int b) {
        #pragma unroll
        for (int p = 0; p < 4; ++p) {
            *(u16x8*)&Ks[b][srr + p * 16][scc] = kr[p];
            #pragma unroll
            for (int e = 0; e < 8; ++e)
                Vs[b][scc + e][srr + p * 16] = vr[p][e];
        }
    };

    const int bb = bh >> 4, h = bh & 15;
    const int qbase = t * 64 + wid * 32;
    const int qg = qbase + lq;

    bf16x8 qf[4];
    #pragma unroll
    for (int kc = 0; kc < 4; ++kc)
        qf[kc] = *(const bf16x8*)&Qg[(size_t)qg * 64 + kc * 16 + hi * 8];

    f32x16 o0, o1;
    #pragma unroll
    for (int j = 0; j < 16; ++j) { o0[j] = 0.f; o1[j] = 0.f; }
    float m = -1e30f, lr = 0.f;

    stage_load(0);
    stage_write(0);
    int cur = 0;

    for (int jb = 0; jb < NJ; ++jb) {
        const int j0 = jb * 64;
        if (jb + 1 < NJ) stage_load(j0 + 64);
        __syncthreads();        // buf[cur] ready

        // ---- S^T = K · Q^T : two 32-kv tiles ----
        f32x16 s0, s1;
        #pragma unroll
        for (int j = 0; j < 16; ++j) { s0[j] = 0.f; s1[j] = 0.f; }
        #pragma unroll
        for (int kc = 0; kc < 4; ++kc) {
            bf16x8 k0 = *(const bf16x8*)&Ks[cur][lq][kc * 16 + hi * 8];
            bf16x8 k1 = *(const bf16x8*)&Ks[cur][32 + lq][kc * 16 + hi * 8];
            s0 = __builtin_amdgcn_mfma_f32_32x32x16_bf16(k0, qf[kc], s0, 0, 0, 0);
            s1 = __builtin_amdgcn_mfma_f32_32x32x16_bf16(k1, qf[kc], s1, 0, 0, 0);
        }
        // ---- causal mask (only fires on the diagonal tile) ----
        if (j0 + 63 > qbase) {
            #pragma unroll
            for (int r = 0; r < 16; ++r) {
                int kv0 = j0 + (r & 3) + 8 * (r >> 2) + 4 * hi;
                if (kv0 > qg)      s0[r] = -1e30f;
                if (kv0 + 32 > qg) s1[r] = -1e30f;
            }
        }
        // ---- row max (lane-local tree + partner swap) ----
        float tm[16];
        #pragma unroll
        for (int j = 0; j < 16; ++j) tm[j] = fmaxf(s0[j], s1[j]);
        #pragma unroll
        for (int w = 8; w > 0; w >>= 1)
            #pragma unroll
            for (int j = 0; j < w; ++j) tm[j] = fmaxf(tm[j], tm[j + w]);
        float pm = fmaxf(tm[0], __shfl_xor(tm[0], 32));
        // ---- defer-max rescale (THR=8) ----
        if (!__all(pm <= m + 8.0f)) {
            float mn = fmaxf(m, pm);
            float corr = __expf(m - mn);
            m = mn; lr *= corr;
            if (lane < 32) cLds[wid][lq] = corr;
            #pragma unroll
            for (int r = 0; r < 16; ++r) {
                float cq = cLds[wid][(r & 3) + 8 * (r >> 2) + 4 * hi];
                o0[r] *= cq; o1[r] *= cq;
            }
        }
        // ---- P = exp(S - m), row sum ----
        float p0[16], p1[16], ts[16];
        #pragma unroll
        for (int j = 0; j < 16; ++j) {
            p0[j] = __expf(s0[j] - m);
            p1[j] = __expf(s1[j] - m);
            ts[j] = p0[j] + p1[j];
        }
        #pragma unroll
        for (int w = 8; w > 0; w >>= 1)
            #pragma unroll
            for (int j = 0; j < w; ++j) ts[j] += ts[j + w];
        lr += ts[0] + __shfl_xor(ts[0], 32);
        // ---- pack P to bf16 pairs (kv-consecutive) ----
        int w0[8], w1[8];
        #pragma unroll
        for (int j = 0; j < 8; ++j) {
            asm("v_cvt_pk_bf16_f32 %0, %1, %2" : "=v"(w0[j]) : "v"(p0[2 * j]), "v"(p0[2 * j + 1]));
            asm("v_cvt_pk_bf16_f32 %0, %1, %2" : "=v"(w1[j]) : "v"(p1[2 * j]), "v"(p1[2 * j + 1]));
        }
        // ---- build PV A-frags in-register ----
        bf16x8 pa[4];
        auto mkfrag = [&](const int* w, int base) -> bf16x8 {
            int x0 = __shfl_xor(w[base + 0], 32);
            int x1 = __shfl_xor(w[base + 1], 32);
            int x2 = __shfl_xor(w[base + 2], 32);
            int x3 = __shfl_xor(w[base + 3], 32);
            int4 f;
            f.x = hi ? x2          : w[base + 0];
            f.y = hi ? x3          : w[base + 1];
            f.z = hi ? w[base + 2] : x0;
            f.w = hi ? w[base + 3] : x1;
            return __builtin_bit_cast(bf16x8, f);
        };
        pa[0] = mkfrag(w0, 0);
        pa[1] = mkfrag(w0, 4);
        pa[2] = mkfrag(w1, 0);
        pa[3] = mkfrag(w1, 4);
        // ---- PV: out[q][d] two 32-d tiles ----
        #pragma unroll
        for (int kc = 0; kc < 4; ++kc) {
            bf16x8 v0 = *(const bf16x8*)&Vs[cur][lq][kc * 16 + hi * 8];
            bf16x8 v1 = *(const bf16x8*)&Vs[cur][32 + lq][kc * 16 + hi * 8];
            o0 = __builtin_amdgcn_mfma_f32_32x32x16_bf16(pa[kc], v0, o0, 0, 0, 0);
            o1 = __builtin_amdgcn_mfma_f32_32x32x16_bf16(pa[kc], v1, o1, 0, 0, 0);
        }

        if (jb + 1 < NJ) stage_write(cur ^ 1);
        cur ^= 1;
    }

    // ---- epilogue: divide by l, store ----
    float inv = 1.0f / lr;
    if (lane < 32) cLds[wid][lq] = inv;
    #pragma unroll
    for (int r = 0; r < 16; ++r) {
        float iq = cLds[wid][(r & 3) + 8 * (r >> 2) + 4 * hi];
        int srow_g = qbase + (r & 3) + 8 * (r >> 2) + 4 * hi;
        size_t rowoff = (size_t)(bb * 2048 + srow_g) * 1024 + h * 64;
        aout[rowoff + lq]      = f2bf(o0[r] * iq);
        aout[rowoff + 32 + lq] = f2bf(o1[r] * iq);
    }
}

extern "C" void kernel_launch(void* const* d_in, const int* in_sizes, int n_in,
                              void* d_out, int out_size, void* d_ws, size_t ws_size,
                              hipStream_t stream) {
    const float* x     = (const float*)d_in[0];
    const float* Wqkv  = (const float*)d_in[2];
    const float* bqkv  = (const float*)d_in[3];
    const float* Wproj = (const float*)d_in[4];
    const float* bproj = (const float*)d_in[5];

    unsigned short* qkvb  = (unsigned short*)d_ws;           // 3*QKV1 bf16 (25.2 MB)
    unsigned short* aoutb = qkvb + 3 * (size_t)QKV1;         // 4096*1024 bf16 (8.4 MB)
    unsigned short* Wt   = aoutb;                 // W_qkv^T bf16 [3072][1024] — dead once attn writes aout
    unsigned short* Wt2  = qkvb;                  // W_proj^T bf16 [1024][1024] — qkv dead after attn
    unsigned short* Xbf  = (unsigned short*)d_out; // X bf16 [4096][1024] in d_out — dead once proj writes d_out

    cvt_f32_bf16<<<4096, 256, 0, stream>>>(x, Xbf, 4096 * 1024 / 4);
    transpose_cvt<<<dim3(96, 32), dim3(32, 8), 0, stream>>>(Wqkv, Wt, 1024, 3072);
    gemm128<0><<<768, 256, 0, stream>>>(Xbf, Wt, bqkv, qkvb, 4096, 3072, 1024);
    attn_fwd<<<dim3(32, 32), 128, 0, stream>>>(qkvb, aoutb);
    transpose_cvt<<<dim3(32, 32), dim3(32, 8), 0, stream>>>(Wproj, Wt2, 1024, 1024);
    gemm128<1><<<256, 256, 0, stream>>>(aoutb, Wt2, bproj, d_out, 4096, 1024, 1024);
}

// Round 7
// 159.048 us; speedup vs baseline: 1.0496x; 1.0496x over previous
//
#include <hip/hip_runtime.h>

typedef __bf16 bf16x8 __attribute__((ext_vector_type(8)));
typedef float f32x4 __attribute__((ext_vector_type(4)));
typedef float f32x16 __attribute__((ext_vector_type(16)));
typedef unsigned short u16x8 __attribute__((ext_vector_type(8)));

constexpr int S_LEN = 2048;
constexpr int QKV1  = 2 * 16 * 2048 * 64;   // elements per Q/K/V tensor = 4194304

__device__ inline unsigned short f2bf(float f) {
    __bf16 h = (__bf16)f;
    return __builtin_bit_cast(unsigned short, h);
}

// global -> LDS async copy, 16B per lane; lds base must be wave-uniform,
// HW writes lane l at base + l*16 (m97/m104).
__device__ inline void gll16(const void* g, void* l) {
    __builtin_amdgcn_global_load_lds(
        (const __attribute__((address_space(1))) unsigned int*)g,
        (__attribute__((address_space(3))) unsigned int*)l,
        16, 0, 0);
}

// ---------------------------------------------------------------------------
// fp32 -> bf16 convert (for X), vectorized float4 -> ushort4.
// ---------------------------------------------------------------------------
__global__ __launch_bounds__(256) void cvt_f32_bf16(
    const float* __restrict__ src, unsigned short* __restrict__ dst, int n4)
{
    int i = blockIdx.x * 256 + threadIdx.x;
    if (i >= n4) return;
    float4 v = ((const float4*)src)[i];
    ushort4 u;
    u.x = f2bf(v.x); u.y = f2bf(v.y); u.z = f2bf(v.z); u.w = f2bf(v.w);
    ((ushort4*)dst)[i] = u;
}

// ---------------------------------------------------------------------------
// Transpose + convert: src [R][C] fp32 -> dst [C][R] bf16
// ---------------------------------------------------------------------------
__global__ __launch_bounds__(256) void transpose_cvt(
    const float* __restrict__ src, unsigned short* __restrict__ dst, int R, int C)
{
    __shared__ float t[32][33];
    const int c0 = blockIdx.x * 32, r0 = blockIdx.y * 32;
    const int tx = threadIdx.x, ty = threadIdx.y;
    #pragma unroll
    for (int i = 0; i < 4; ++i)
        t[ty * 4 + i][tx] = src[(size_t)(r0 + ty * 4 + i) * C + c0 + tx];
    __syncthreads();
    #pragma unroll
    for (int i = 0; i < 4; ++i)
        dst[(size_t)(c0 + ty * 4 + i) * R + r0 + tx] = f2bf(t[tx][ty * 4 + i]);
}

// ---------------------------------------------------------------------------
// m97-structure bf16 GEMM. EPI 0: qkv scatter-store; Q scaled 0.125, Q/K as
// [bh][s][d], V stored TRANSPOSED as Vt[bh][d][s]. EPI 1: fp32 +bias store.
// ---------------------------------------------------------------------------
template<int EPI>
__global__ __launch_bounds__(256) void gemm128(
    const unsigned short* __restrict__ A,   // [M][K] bf16
    const unsigned short* __restrict__ Bt,  // [N][K] bf16
    const float* __restrict__ bias,         // [N]
    void* __restrict__ outp, int M, int N, int K)
{
    __shared__ unsigned short As[128 * 64];
    __shared__ unsigned short Bs[128 * 64];
    const int tid = threadIdx.x, lane = tid & 63, wid = tid >> 6;
    const int q = lane & 15, g = lane >> 4;
    const int wr = wid >> 1, wc = wid & 1;

    const int nbx = N >> 7;
    const int cpx = gridDim.x >> 3;
    const int bid = blockIdx.x;
    const int swz = (bid & 7) * cpx + (bid >> 3);    // bijective, nwg%8==0
    const int m0 = (swz / nbx) * 128, n0 = (swz % nbx) * 128;

    const int lrow = lane >> 3, lcol = (lane & 7) * 8;  // within-chunk row/col

    f32x4 acc[4][4];
    #pragma unroll
    for (int i = 0; i < 4; ++i)
        #pragma unroll
        for (int j = 0; j < 4; ++j) acc[i][j] = (f32x4){0.f, 0.f, 0.f, 0.f};

    for (int k0 = 0; k0 < K; k0 += 64) {
        #pragma unroll
        for (int i = 0; i < 4; ++i) {       // 4 chunks/operand/wave, 1KB each
            int c = wid * 4 + i;
            int row = c * 8 + lrow;
            gll16(&A [(size_t)(m0 + row) * K + k0 + lcol], &As[c * 512]);
            gll16(&Bt[(size_t)(n0 + row) * K + k0 + lcol], &Bs[c * 512]);
        }
        __syncthreads();                    // compiler drains vmcnt before barrier
        #pragma unroll
        for (int h = 0; h < 2; ++h) {
            bf16x8 a[4], b[4];
            #pragma unroll
            for (int mi = 0; mi < 4; ++mi)
                a[mi] = *(const bf16x8*)&As[(wr * 64 + mi * 16 + q) * 64 + h * 32 + g * 8];
            #pragma unroll
            for (int ni = 0; ni < 4; ++ni)
                b[ni] = *(const bf16x8*)&Bs[(wc * 64 + ni * 16 + q) * 64 + h * 32 + g * 8];
            #pragma unroll
            for (int mi = 0; mi < 4; ++mi)
                #pragma unroll
                for (int ni = 0; ni < 4; ++ni)
                    acc[mi][ni] = __builtin_amdgcn_mfma_f32_16x16x32_bf16(a[mi], b[ni], acc[mi][ni], 0, 0, 0);
        }
        __syncthreads();
    }

    #pragma unroll
    for (int mi = 0; mi < 4; ++mi)
        #pragma unroll
        for (int ni = 0; ni < 4; ++ni)
            #pragma unroll
            for (int r = 0; r < 4; ++r) {
                int m = m0 + wr * 64 + mi * 16 + g * 4 + r;
                int n = n0 + wc * 64 + ni * 16 + q;
                float v = acc[mi][ni][r] + bias[n];
                if (EPI == 0) {
                    int t = n >> 10, rem = n & 1023;
                    if (t == 0) v *= 0.125f;          // q * rsqrt(64)
                    int h2 = rem >> 6, kk = rem & 63;
                    int bb = m >> 11, s = m & 2047;
                    size_t off;
                    if (t == 2)   // V transposed: Vt[bh][d][s]
                        off = 2 * (size_t)QKV1 + ((size_t)(bb * 16 + h2) * 64 + kk) * 2048 + s;
                    else          // Q/K: [bh][s][d]
                        off = (size_t)t * QKV1 + ((size_t)(bb * 16 + h2) * 2048 + s) * 64 + kk;
                    ((unsigned short*)outp)[off] = f2bf(v);
                } else {
                    ((float*)outp)[(size_t)m * N + n] = v;
                }
            }
}

// ---------------------------------------------------------------------------
// Kernel 2: causal flash attention — EXACT R5 structure (2-wave blocks, LDS
// K/V double-buffer, LPT), with ONE change: V staged from the transposed
// global layout Vt[bh][d][s] via LINEAR row copies (no in-LDS transpose
// scatter -> kills the measured 16-way bank-conflict on V writes).
// ---------------------------------------------------------------------------
__global__ __launch_bounds__(128) void attn_fwd(
    const unsigned short* __restrict__ qkv, unsigned short* __restrict__ aout)
{
    __shared__ unsigned short Ks[2][64][72];   // [buf][kv][d]
    __shared__ unsigned short Vs[2][64][72];   // [buf][d][kv_local]
    __shared__ float cLds[2][32];
    const int tid = threadIdx.x, lane = tid & 63, wid = tid >> 6;
    const int hi = lane >> 5, lq = lane & 31;
    const int bh = blockIdx.x;
    const int t  = 31 - (int)blockIdx.y;        // LPT: longest blocks first
    const int NJ = t + 1;
    const unsigned short* Qg = qkv + (size_t)bh * S_LEN * 64;
    const unsigned short* Kg = qkv + (size_t)QKV1 + (size_t)bh * S_LEN * 64;
    const unsigned short* Vt = qkv + 2 * (size_t)QKV1 + (size_t)bh * 64 * S_LEN; // [d][s]

    // staging: 128 threads, contiguous 16B/lane chunks
    const int srr = tid >> 3, scc = (tid & 7) * 8;
    u16x8 kr[4], vr[4];
    auto stage_load = [&](int j0) {
        #pragma unroll
        for (int p = 0; p < 4; ++p) {
            kr[p] = *(const u16x8*)&Kg[(size_t)(j0 + srr + p * 16) * 64 + scc];
            vr[p] = *(const u16x8*)&Vt[(size_t)(srr + p * 16) * 2048 + j0 + scc];
        }
    };
    auto stage_write = [&](int b) {
        #pragma unroll
        for (int p = 0; p < 4; ++p) {
            *(u16x8*)&Ks[b][srr + p * 16][scc] = kr[p];
            *(u16x8*)&Vs[b][srr + p * 16][scc] = vr[p];   // linear copy, no scatter
        }
    };

    const int bb = bh >> 4, h = bh & 15;
    const int qbase = t * 64 + wid * 32;
    const int qg = qbase + lq;

    bf16x8 qf[4];
    #pragma unroll
    for (int kc = 0; kc < 4; ++kc)
        qf[kc] = *(const bf16x8*)&Qg[(size_t)qg * 64 + kc * 16 + hi * 8];

    f32x16 o0, o1;
    #pragma unroll
    for (int j = 0; j < 16; ++j) { o0[j] = 0.f; o1[j] = 0.f; }
    float m = -1e30f, lr = 0.f;

    stage_load(0);
    stage_write(0);
    int cur = 0;

    for (int jb = 0; jb < NJ; ++jb) {
        const int j0 = jb * 64;
        if (jb + 1 < NJ) stage_load(j0 + 64);
        __syncthreads();        // buf[cur] ready

        // ---- S^T = K · Q^T : two 32-kv tiles ----
        f32x16 s0, s1;
        #pragma unroll
        for (int j = 0; j < 16; ++j) { s0[j] = 0.f; s1[j] = 0.f; }
        #pragma unroll
        for (int kc = 0; kc < 4; ++kc) {
            bf16x8 k0 = *(const bf16x8*)&Ks[cur][lq][kc * 16 + hi * 8];
            bf16x8 k1 = *(const bf16x8*)&Ks[cur][32 + lq][kc * 16 + hi * 8];
            s0 = __builtin_amdgcn_mfma_f32_32x32x16_bf16(k0, qf[kc], s0, 0, 0, 0);
            s1 = __builtin_amdgcn_mfma_f32_32x32x16_bf16(k1, qf[kc], s1, 0, 0, 0);
        }
        // ---- causal mask (only fires on the diagonal tile) ----
        if (j0 + 63 > qbase) {
            #pragma unroll
            for (int r = 0; r < 16; ++r) {
                int kv0 = j0 + (r & 3) + 8 * (r >> 2) + 4 * hi;
                if (kv0 > qg)      s0[r] = -1e30f;
                if (kv0 + 32 > qg) s1[r] = -1e30f;
            }
        }
        // ---- row max (lane-local tree + partner swap) ----
        float tm[16];
        #pragma unroll
        for (int j = 0; j < 16; ++j) tm[j] = fmaxf(s0[j], s1[j]);
        #pragma unroll
        for (int w = 8; w > 0; w >>= 1)
            #pragma unroll
            for (int j = 0; j < w; ++j) tm[j] = fmaxf(tm[j], tm[j + w]);
        float pm = fmaxf(tm[0], __shfl_xor(tm[0], 32));
        // ---- defer-max rescale (THR=8) ----
        if (!__all(pm <= m + 8.0f)) {
            float mn = fmaxf(m, pm);
            float corr = __expf(m - mn);
            m = mn; lr *= corr;
            if (lane < 32) cLds[wid][lq] = corr;
            #pragma unroll
            for (int r = 0; r < 16; ++r) {
                float cq = cLds[wid][(r & 3) + 8 * (r >> 2) + 4 * hi];
                o0[r] *= cq; o1[r] *= cq;
            }
        }
        // ---- P = exp(S - m), row sum ----
        float p0[16], p1[16], ts[16];
        #pragma unroll
        for (int j = 0; j < 16; ++j) {
            p0[j] = __expf(s0[j] - m);
            p1[j] = __expf(s1[j] - m);
            ts[j] = p0[j] + p1[j];
        }
        #pragma unroll
        for (int w = 8; w > 0; w >>= 1)
            #pragma unroll
            for (int j = 0; j < w; ++j) ts[j] += ts[j + w];
        lr += ts[0] + __shfl_xor(ts[0], 32);
        // ---- pack P to bf16 pairs (kv-consecutive) ----
        int w0[8], w1[8];
        #pragma unroll
        for (int j = 0; j < 8; ++j) {
            asm("v_cvt_pk_bf16_f32 %0, %1, %2" : "=v"(w0[j]) : "v"(p0[2 * j]), "v"(p0[2 * j + 1]));
            asm("v_cvt_pk_bf16_f32 %0, %1, %2" : "=v"(w1[j]) : "v"(p1[2 * j]), "v"(p1[2 * j + 1]));
        }
        // ---- build PV A-frags in-register ----
        bf16x8 pa[4];
        auto mkfrag = [&](const int* w, int base) -> bf16x8 {
            int x0 = __shfl_xor(w[base + 0], 32);
            int x1 = __shfl_xor(w[base + 1], 32);
            int x2 = __shfl_xor(w[base + 2], 32);
            int x3 = __shfl_xor(w[base + 3], 32);
            int4 f;
            f.x = hi ? x2          : w[base + 0];
            f.y = hi ? x3          : w[base + 1];
            f.z = hi ? w[base + 2] : x0;
            f.w = hi ? w[base + 3] : x1;
            return __builtin_bit_cast(bf16x8, f);
        };
        pa[0] = mkfrag(w0, 0);
        pa[1] = mkfrag(w0, 4);
        pa[2] = mkfrag(w1, 0);
        pa[3] = mkfrag(w1, 4);
        // ---- PV: out[q][d] two 32-d tiles ----
        #pragma unroll
        for (int kc = 0; kc < 4; ++kc) {
            bf16x8 v0 = *(const bf16x8*)&Vs[cur][lq][kc * 16 + hi * 8];
            bf16x8 v1 = *(const bf16x8*)&Vs[cur][32 + lq][kc * 16 + hi * 8];
            o0 = __builtin_amdgcn_mfma_f32_32x32x16_bf16(pa[kc], v0, o0, 0, 0, 0);
            o1 = __builtin_amdgcn_mfma_f32_32x32x16_bf16(pa[kc], v1, o1, 0, 0, 0);
        }

        if (jb + 1 < NJ) stage_write(cur ^ 1);
        cur ^= 1;
    }

    // ---- epilogue: divide by l, store ----
    float inv = 1.0f / lr;
    if (lane < 32) cLds[wid][lq] = inv;
    #pragma unroll
    for (int r = 0; r < 16; ++r) {
        float iq = cLds[wid][(r & 3) + 8 * (r >> 2) + 4 * hi];
        int srow_g = qbase + (r & 3) + 8 * (r >> 2) + 4 * hi;
        size_t rowoff = (size_t)(bb * 2048 + srow_g) * 1024 + h * 64;
        aout[rowoff + lq]      = f2bf(o0[r] * iq);
        aout[rowoff + 32 + lq] = f2bf(o1[r] * iq);
    }
}

extern "C" void kernel_launch(void* const* d_in, const int* in_sizes, int n_in,
                              void* d_out, int out_size, void* d_ws, size_t ws_size,
                              hipStream_t stream) {
    const float* x     = (const float*)d_in[0];
    const float* Wqkv  = (const float*)d_in[2];
    const float* bqkv  = (const float*)d_in[3];
    const float* Wproj = (const float*)d_in[4];
    const float* bproj = (const float*)d_in[5];

    unsigned short* qkvb  = (unsigned short*)d_ws;           // Q,K [bh][s][d] + Vt [bh][d][s]
    unsigned short* aoutb = qkvb + 3 * (size_t)QKV1;         // 4096*1024 bf16
    unsigned short* Wt   = aoutb;                 // W_qkv^T bf16 — dead once attn writes aout
    unsigned short* Wt2  = qkvb;                  // W_proj^T bf16 — qkv dead after attn
    unsigned short* Xbf  = (unsigned short*)d_out; // X bf16 in d_out — dead once proj writes d_out

    cvt_f32_bf16<<<4096, 256, 0, stream>>>(x, Xbf, 4096 * 1024 / 4);
    transpose_cvt<<<dim3(96, 32), dim3(32, 8), 0, stream>>>(Wqkv, Wt, 1024, 3072);
    gemm128<0><<<768, 256, 0, stream>>>(Xbf, Wt, bqkv, qkvb, 4096, 3072, 1024);
    attn_fwd<<<dim3(32, 32), 128, 0, stream>>>(qkvb, aoutb);
    transpose_cvt<<<dim3(32, 32), dim3(32, 8), 0, stream>>>(Wproj, Wt2, 1024, 1024);
    gemm128<1><<<256, 256, 0, stream>>>(aoutb, Wt2, bproj, d_out, 4096, 1024, 1024);
}

// Round 8
// 131.696 us; speedup vs baseline: 1.2675x; 1.2077x over previous
//
#include <hip/hip_runtime.h>

typedef __bf16 bf16x8 __attribute__((ext_vector_type(8)));
typedef float f32x4 __attribute__((ext_vector_type(4)));
typedef float f32x16 __attribute__((ext_vector_type(16)));
typedef unsigned short u16x8 __attribute__((ext_vector_type(8)));

constexpr int S_LEN = 2048;
constexpr int QKV1  = 2 * 16 * 2048 * 64;   // elements per Q/K/V tensor = 4194304

__device__ inline unsigned short f2bf(float f) {
    __bf16 h = (__bf16)f;
    return __builtin_bit_cast(unsigned short, h);
}

// global -> LDS async copy, 16B per lane; lds base must be wave-uniform,
// HW writes lane l at base + l*16 (m97/m104).
__device__ inline void gll16(const void* g, void* l) {
    __builtin_amdgcn_global_load_lds(
        (const __attribute__((address_space(1))) unsigned int*)g,
        (__attribute__((address_space(3))) unsigned int*)l,
        16, 0, 0);
}

// ---------------------------------------------------------------------------
// fp32 -> bf16 convert (for X), vectorized float4 -> ushort4.
// ---------------------------------------------------------------------------
__global__ __launch_bounds__(256) void cvt_f32_bf16(
    const float* __restrict__ src, unsigned short* __restrict__ dst, int n4)
{
    int i = blockIdx.x * 256 + threadIdx.x;
    if (i >= n4) return;
    float4 v = ((const float4*)src)[i];
    ushort4 u;
    u.x = f2bf(v.x); u.y = f2bf(v.y); u.z = f2bf(v.z); u.w = f2bf(v.w);
    ((ushort4*)dst)[i] = u;
}

// ---------------------------------------------------------------------------
// Transpose + convert: src [R][C] fp32 -> dst [C][R] bf16
// ---------------------------------------------------------------------------
__global__ __launch_bounds__(256) void transpose_cvt(
    const float* __restrict__ src, unsigned short* __restrict__ dst, int R, int C)
{
    __shared__ float t[32][33];
    const int c0 = blockIdx.x * 32, r0 = blockIdx.y * 32;
    const int tx = threadIdx.x, ty = threadIdx.y;
    #pragma unroll
    for (int i = 0; i < 4; ++i)
        t[ty * 4 + i][tx] = src[(size_t)(r0 + ty * 4 + i) * C + c0 + tx];
    __syncthreads();
    #pragma unroll
    for (int i = 0; i < 4; ++i)
        dst[(size_t)(c0 + ty * 4 + i) * R + r0 + tx] = f2bf(t[tx][ty * 4 + i]);
}

// ---------------------------------------------------------------------------
// bf16 GEMM, 2-phase double-buffered: 128x128 tile, BK=32, 4 waves (2x2).
// LDS [2][128][32] (32KB total, 3 blocks/CU). Next K-tile's global_load_lds
// issued BEFORE compute -> load latency hides under MFMA; ONE barrier/step.
// Bank-conflict fix (rule #21 both-sides): source-swizzled gll16 + XOR read
// (slot ^= row&3) -> 16-way -> 4-way on ds_read_b128.
// EPI 0: qkv scatter (Q scaled, Q/K [bh][s][d], V transposed Vt[bh][d][s]).
// EPI 1: fp32 +bias store.
// ---------------------------------------------------------------------------
template<int EPI>
__global__ __launch_bounds__(256) void gemm128(
    const unsigned short* __restrict__ A,   // [M][K] bf16
    const unsigned short* __restrict__ Bt,  // [N][K] bf16
    const float* __restrict__ bias,         // [N]
    void* __restrict__ outp, int M, int N, int K)
{
    __shared__ unsigned short As[2][128 * 32];
    __shared__ unsigned short Bs[2][128 * 32];
    const int tid = threadIdx.x, lane = tid & 63, wid = tid >> 6;
    const int q = lane & 15, g = lane >> 4;
    const int wr = wid >> 1, wc = wid & 1;

    const int nbx = N >> 7;
    const int cpx = gridDim.x >> 3;
    const int bid = blockIdx.x;
    const int swz = (bid & 7) * cpx + (bid >> 3);    // bijective, nwg%8==0
    const int m0 = (swz / nbx) * 128, n0 = (swz % nbx) * 128;

    // staging: per wave 2 chunks/operand; chunk c = 16 rows x 32 cols (1KB).
    // lane l: row = c*16 + (l>>2); SOURCE slot = (l&3) ^ (row&3)  [swizzle]
    const int srow_in = lane >> 2;
    const int sslot   = (lane & 3) ^ (srow_in & 3);
    auto stage = [&](int buf, int k0) {
        #pragma unroll
        for (int i = 0; i < 2; ++i) {
            int c = wid * 2 + i;
            int row = c * 16 + srow_in;
            gll16(&A [(size_t)(m0 + row) * K + k0 + sslot * 8], &As[buf][c * 512]);
            gll16(&Bt[(size_t)(n0 + row) * K + k0 + sslot * 8], &Bs[buf][c * 512]);
        }
    };

    f32x4 acc[4][4];
    #pragma unroll
    for (int i = 0; i < 4; ++i)
        #pragma unroll
        for (int j = 0; j < 4; ++j) acc[i][j] = (f32x4){0.f, 0.f, 0.f, 0.f};

    const int NSTEP = K >> 5;
    const int rslot = (g ^ (q & 3)) * 8;             // read-side swizzle
    stage(0, 0);
    __syncthreads();
    int cur = 0;

    for (int ks = 0; ks < NSTEP; ++ks) {
        if (ks + 1 < NSTEP) stage(cur ^ 1, (ks + 1) * 32);  // fly under MFMA
        bf16x8 a[4], b[4];
        #pragma unroll
        for (int mi = 0; mi < 4; ++mi)
            a[mi] = *(const bf16x8*)&As[cur][(wr * 64 + mi * 16 + q) * 32 + rslot];
        #pragma unroll
        for (int ni = 0; ni < 4; ++ni)
            b[ni] = *(const bf16x8*)&Bs[cur][(wc * 64 + ni * 16 + q) * 32 + rslot];
        #pragma unroll
        for (int mi = 0; mi < 4; ++mi)
            #pragma unroll
            for (int ni = 0; ni < 4; ++ni)
                acc[mi][ni] = __builtin_amdgcn_mfma_f32_16x16x32_bf16(a[mi], b[ni], acc[mi][ni], 0, 0, 0);
        __syncthreads();                  // drains vmcnt (next buf ready) + lds
        cur ^= 1;
    }

    #pragma unroll
    for (int mi = 0; mi < 4; ++mi)
        #pragma unroll
        for (int ni = 0; ni < 4; ++ni)
            #pragma unroll
            for (int r = 0; r < 4; ++r) {
                int m = m0 + wr * 64 + mi * 16 + g * 4 + r;
                int n = n0 + wc * 64 + ni * 16 + q;
                float v = acc[mi][ni][r] + bias[n];
                if (EPI == 0) {
                    int t = n >> 10, rem = n & 1023;
                    if (t == 0) v *= 0.125f;          // q * rsqrt(64)
                    int h2 = rem >> 6, kk = rem & 63;
                    int bb = m >> 11, s = m & 2047;
                    size_t off;
                    if (t == 2)   // V transposed: Vt[bh][d][s]
                        off = 2 * (size_t)QKV1 + ((size_t)(bb * 16 + h2) * 64 + kk) * 2048 + s;
                    else          // Q/K: [bh][s][d]
                        off = (size_t)t * QKV1 + ((size_t)(bb * 16 + h2) * 2048 + s) * 64 + kk;
                    ((unsigned short*)outp)[off] = f2bf(v);
                } else {
                    ((float*)outp)[(size_t)m * N + n] = v;
                }
            }
}

// ---------------------------------------------------------------------------
// Kernel 2: causal flash attention (unchanged from R7 — known-good).
// ---------------------------------------------------------------------------
__global__ __launch_bounds__(128) void attn_fwd(
    const unsigned short* __restrict__ qkv, unsigned short* __restrict__ aout)
{
    __shared__ unsigned short Ks[2][64][72];   // [buf][kv][d]
    __shared__ unsigned short Vs[2][64][72];   // [buf][d][kv_local]
    __shared__ float cLds[2][32];
    const int tid = threadIdx.x, lane = tid & 63, wid = tid >> 6;
    const int hi = lane >> 5, lq = lane & 31;
    const int bh = blockIdx.x;
    const int t  = 31 - (int)blockIdx.y;        // LPT: longest blocks first
    const int NJ = t + 1;
    const unsigned short* Qg = qkv + (size_t)bh * S_LEN * 64;
    const unsigned short* Kg = qkv + (size_t)QKV1 + (size_t)bh * S_LEN * 64;
    const unsigned short* Vt = qkv + 2 * (size_t)QKV1 + (size_t)bh * 64 * S_LEN; // [d][s]

    const int srr = tid >> 3, scc = (tid & 7) * 8;
    u16x8 kr[4], vr[4];
    auto stage_load = [&](int j0) {
        #pragma unroll
        for (int p = 0; p < 4; ++p) {
            kr[p] = *(const u16x8*)&Kg[(size_t)(j0 + srr + p * 16) * 64 + scc];
            vr[p] = *(const u16x8*)&Vt[(size_t)(srr + p * 16) * 2048 + j0 + scc];
        }
    };
    auto stage_write = [&](int b) {
        #pragma unroll
        for (int p = 0; p < 4; ++p) {
            *(u16x8*)&Ks[b][srr + p * 16][scc] = kr[p];
            *(u16x8*)&Vs[b][srr + p * 16][scc] = vr[p];   // linear copy, no scatter
        }
    };

    const int bb = bh >> 4, h = bh & 15;
    const int qbase = t * 64 + wid * 32;
    const int qg = qbase + lq;

    bf16x8 qf[4];
    #pragma unroll
    for (int kc = 0; kc < 4; ++kc)
        qf[kc] = *(const bf16x8*)&Qg[(size_t)qg * 64 + kc * 16 + hi * 8];

    f32x16 o0, o1;
    #pragma unroll
    for (int j = 0; j < 16; ++j) { o0[j] = 0.f; o1[j] = 0.f; }
    float m = -1e30f, lr = 0.f;

    stage_load(0);
    stage_write(0);
    int cur = 0;

    for (int jb = 0; jb < NJ; ++jb) {
        const int j0 = jb * 64;
        if (jb + 1 < NJ) stage_load(j0 + 64);
        __syncthreads();        // buf[cur] ready

        f32x16 s0, s1;
        #pragma unroll
        for (int j = 0; j < 16; ++j) { s0[j] = 0.f; s1[j] = 0.f; }
        #pragma unroll
        for (int kc = 0; kc < 4; ++kc) {
            bf16x8 k0 = *(const bf16x8*)&Ks[cur][lq][kc * 16 + hi * 8];
            bf16x8 k1 = *(const bf16x8*)&Ks[cur][32 + lq][kc * 16 + hi * 8];
            s0 = __builtin_amdgcn_mfma_f32_32x32x16_bf16(k0, qf[kc], s0, 0, 0, 0);
            s1 = __builtin_amdgcn_mfma_f32_32x32x16_bf16(k1, qf[kc], s1, 0, 0, 0);
        }
        if (j0 + 63 > qbase) {
            #pragma unroll
            for (int r = 0; r < 16; ++r) {
                int kv0 = j0 + (r & 3) + 8 * (r >> 2) + 4 * hi;
                if (kv0 > qg)      s0[r] = -1e30f;
                if (kv0 + 32 > qg) s1[r] = -1e30f;
            }
        }
        float tm[16];
        #pragma unroll
        for (int j = 0; j < 16; ++j) tm[j] = fmaxf(s0[j], s1[j]);
        #pragma unroll
        for (int w = 8; w > 0; w >>= 1)
            #pragma unroll
            for (int j = 0; j < w; ++j) tm[j] = fmaxf(tm[j], tm[j + w]);
        float pm = fmaxf(tm[0], __shfl_xor(tm[0], 32));
        if (!__all(pm <= m + 8.0f)) {
            float mn = fmaxf(m, pm);
            float corr = __expf(m - mn);
            m = mn; lr *= corr;
            if (lane < 32) cLds[wid][lq] = corr;
            #pragma unroll
            for (int r = 0; r < 16; ++r) {
                float cq = cLds[wid][(r & 3) + 8 * (r >> 2) + 4 * hi];
                o0[r] *= cq; o1[r] *= cq;
            }
        }
        float p0[16], p1[16], ts[16];
        #pragma unroll
        for (int j = 0; j < 16; ++j) {
            p0[j] = __expf(s0[j] - m);
            p1[j] = __expf(s1[j] - m);
            ts[j] = p0[j] + p1[j];
        }
        #pragma unroll
        for (int w = 8; w > 0; w >>= 1)
            #pragma unroll
            for (int j = 0; j < w; ++j) ts[j] += ts[j + w];
        lr += ts[0] + __shfl_xor(ts[0], 32);
        int w0[8], w1[8];
        #pragma unroll
        for (int j = 0; j < 8; ++j) {
            asm("v_cvt_pk_bf16_f32 %0, %1, %2" : "=v"(w0[j]) : "v"(p0[2 * j]), "v"(p0[2 * j + 1]));
            asm("v_cvt_pk_bf16_f32 %0, %1, %2" : "=v"(w1[j]) : "v"(p1[2 * j]), "v"(p1[2 * j + 1]));
        }
        bf16x8 pa[4];
        auto mkfrag = [&](const int* w, int base) -> bf16x8 {
            int x0 = __shfl_xor(w[base + 0], 32);
            int x1 = __shfl_xor(w[base + 1], 32);
            int x2 = __shfl_xor(w[base + 2], 32);
            int x3 = __shfl_xor(w[base + 3], 32);
            int4 f;
            f.x = hi ? x2          : w[base + 0];
            f.y = hi ? x3          : w[base + 1];
            f.z = hi ? w[base + 2] : x0;
            f.w = hi ? w[base + 3] : x1;
            return __builtin_bit_cast(bf16x8, f);
        };
        pa[0] = mkfrag(w0, 0);
        pa[1] = mkfrag(w0, 4);
        pa[2] = mkfrag(w1, 0);
        pa[3] = mkfrag(w1, 4);
        #pragma unroll
        for (int kc = 0; kc < 4; ++kc) {
            bf16x8 v0 = *(const bf16x8*)&Vs[cur][lq][kc * 16 + hi * 8];
            bf16x8 v1 = *(const bf16x8*)&Vs[cur][32 + lq][kc * 16 + hi * 8];
            o0 = __builtin_amdgcn_mfma_f32_32x32x16_bf16(pa[kc], v0, o0, 0, 0, 0);
            o1 = __builtin_amdgcn_mfma_f32_32x32x16_bf16(pa[kc], v1, o1, 0, 0, 0);
        }

        if (jb + 1 < NJ) stage_write(cur ^ 1);
        cur ^= 1;
    }

    float inv = 1.0f / lr;
    if (lane < 32) cLds[wid][lq] = inv;
    #pragma unroll
    for (int r = 0; r < 16; ++r) {
        float iq = cLds[wid][(r & 3) + 8 * (r >> 2) + 4 * hi];
        int srow_g = qbase + (r & 3) + 8 * (r >> 2) + 4 * hi;
        size_t rowoff = (size_t)(bb * 2048 + srow_g) * 1024 + h * 64;
        aout[rowoff + lq]      = f2bf(o0[r] * iq);
        aout[rowoff + 32 + lq] = f2bf(o1[r] * iq);
    }
}

extern "C" void kernel_launch(void* const* d_in, const int* in_sizes, int n_in,
                              void* d_out, int out_size, void* d_ws, size_t ws_size,
                              hipStream_t stream) {
    const float* x     = (const float*)d_in[0];
    const float* Wqkv  = (const float*)d_in[2];
    const float* bqkv  = (const float*)d_in[3];
    const float* Wproj = (const float*)d_in[4];
    const float* bproj = (const float*)d_in[5];

    unsigned short* qkvb  = (unsigned short*)d_ws;           // Q,K [bh][s][d] + Vt [bh][d][s]
    unsigned short* aoutb = qkvb + 3 * (size_t)QKV1;         // 4096*1024 bf16
    unsigned short* Wt   = aoutb;                 // W_qkv^T bf16 — dead once attn writes aout
    unsigned short* Wt2  = qkvb;                  // W_proj^T bf16 — qkv dead after attn
    unsigned short* Xbf  = (unsigned short*)d_out; // X bf16 in d_out — dead once proj writes d_out

    cvt_f32_bf16<<<4096, 256, 0, stream>>>(x, Xbf, 4096 * 1024 / 4);
    transpose_cvt<<<dim3(96, 32), dim3(32, 8), 0, stream>>>(Wqkv, Wt, 1024, 3072);
    gemm128<0><<<768, 256, 0, stream>>>(Xbf, Wt, bqkv, qkvb, 4096, 3072, 1024);
    attn_fwd<<<dim3(32, 32), 128, 0, stream>>>(qkvb, aoutb);
    transpose_cvt<<<dim3(32, 32), dim3(32, 8), 0, stream>>>(Wproj, Wt2, 1024, 1024);
    gemm128<1><<<256, 256, 0, stream>>>(aoutb, Wt2, bproj, d_out, 4096, 1024, 1024);
}